// Round 11
// baseline (537.732 us; speedup 1.0000x reference)
//
#include <hip/hip_runtime.h>
#include <hip/hip_bf16.h>

typedef __hip_bfloat16 bf16;

typedef __attribute__((ext_vector_type(8))) short frag8;
typedef __attribute__((ext_vector_type(4))) float f32x4;

__device__ __forceinline__ bf16 f2bf(float f) { return __float2bfloat16(f); }

__device__ __forceinline__ float u16f(unsigned short u) {
  union { unsigned int i; float f; } c; c.i = ((unsigned int)u) << 16; return c.f;
}
__device__ __forceinline__ unsigned short bfbits(float f) {
  union { bf16 b; unsigned short u; } c; c.b = __float2bfloat16(f); return c.u;
}
__device__ __forceinline__ float tof(float x) { return x; }
__device__ __forceinline__ float tof(bf16 x)  { return __bfloat162float(x); }

// async 16B global->LDS copy (m97 pattern)
__device__ __forceinline__ void gload_lds16(const bf16* g, short* l) {
  __builtin_amdgcn_global_load_lds(
      (const __attribute__((address_space(1))) void*)g,
      (__attribute__((address_space(3))) void*)l, 16, 0, 0);
}

// VALU-pipe cross-lane reduce within each 16-lane row (DPP, no DS ops).
// Transient temps only -- no persistent register cost (R8/R9 lessons).
template<int CTRL>
__device__ __forceinline__ float dppmax(float x) {
  return fmaxf(x, __int_as_float(__builtin_amdgcn_update_dpp(
      0, __float_as_int(x), CTRL, 0xF, 0xF, true)));
}
__device__ __forceinline__ float rowmax16(float x) {
  x = dppmax<0x128>(x);  // row_ror:8
  x = dppmax<0x124>(x);  // row_ror:4
  x = dppmax<0x4E>(x);   // quad_perm {2,3,0,1} = xor2
  x = dppmax<0xB1>(x);   // quad_perm {1,0,3,2} = xor1
  return x;
}
template<int CTRL>
__device__ __forceinline__ float dppadd(float x) {
  return x + __int_as_float(__builtin_amdgcn_update_dpp(
      0, __float_as_int(x), CTRL, 0xF, 0xF, true));
}
__device__ __forceinline__ float rowsum16(float x) {
  x = dppadd<0x128>(x);
  x = dppadd<0x124>(x);
  x = dppadd<0x4E>(x);
  x = dppadd<0xB1>(x);
  return x;
}

#define EP_PLAIN 0
#define EP_RK    2
#define EP_Q     3
#define EP_KV    4

// batched fp32 -> bf16 convert: 8 segments in one launch
struct CvtArgs {
  const float* src[8];
  bf16* dst[8];
  int cum[9];          // cumulative n4 boundaries
};
__global__ __launch_bounds__(256)
void cvt8(CvtArgs a)
{
  const int i = blockIdx.x * 256 + threadIdx.x;
  if (i >= a.cum[8]) return;
  int seg = 7;
  #pragma unroll
  for (int s2 = 6; s2 >= 0; --s2) if (i < a.cum[s2 + 1]) seg = s2;
  const int o = i - a.cum[seg];
  float4 v = ((const float4*)a.src[seg])[o];
  ushort4 u;
  u.x = bfbits(v.x); u.y = bfbits(v.y); u.z = bfbits(v.z); u.w = bfbits(v.w);
  ((ushort4*)a.dst[seg])[o] = u;
}

// MFMA GEMM: C[M,N] = A[M,K] @ W[N,K]^T, bf16 in, fp32 accum.
// 128x128 tile, 4 waves (2x2), double-buffered stage-ahead (R4).
// R11: template BKT. R10 counters: FF2 (grid 256 = 1 block/CU, K=4096) is
// drain-count-bound: 1760 cy/K-step vs 320 cy MFMA, nothing co-resident to
// hide the stage drain, + 8-way bank conflicts (4.19M) on stride-64B reads.
// BKT=64 for the 1-block/CU calls (FF2/Wo/Q/rk): halves drain events,
// doubles per-step MFMA cover, LDS 64KB (free at 1 block/CU). 128-B rows
// would be 16-way-conflicted, so the BKT=64 path uses the fattn-validated
// XOR swizzle (rule #21: pre-swizzled global source + swizzled ds_read)
// -> 2-way (free). BKT=32 path (KV/FF1, 4 blocks/CU) is byte-identical
// to R10.
template<typename TRES, int BKT>
__global__ __launch_bounds__(256)
void mgemm(const bf16* __restrict__ A, const bf16* __restrict__ W,
           const float* __restrict__ bias, const TRES* __restrict__ res,
           bf16* __restrict__ out,
           bf16* __restrict__ qwb, bf16* __restrict__ qrb,
           bf16* __restrict__ kbo, bf16* __restrict__ vto,
           const float* __restrict__ rwbias, const float* __restrict__ rrbias,
           int M, int N, int K, int mode, int relu)
{
  __shared__ __align__(16) short sAm[2][128 * BKT];
  __shared__ __align__(16) short sBm[2][128 * BKT];
  const int tid  = threadIdx.x;
  const int lane = tid & 63;
  const int wave = tid >> 6;
  const int quad = lane >> 4;
  const int l15  = lane & 15;
  const int m0 = blockIdx.y * 128;
  const int n0 = blockIdx.x * 128;
  const int wm = (wave >> 1) * 64;
  const int wn = (wave & 1) * 64;

  const int lr = tid >> 2;
  const int lc = (tid & 3) << 3;

  const bf16* aptr0 = A + (size_t)(m0 + lr) * K + lc;
  const bf16* aptr1 = aptr0 + (size_t)64 * K;
  const bf16* wptr0 = W + (size_t)(n0 + lr) * K + lc;
  const bf16* wptr1 = wptr0 + (size_t)64 * K;

  f32x4 acc[4][4] = {};

  // stage K-slice [kk,kk+BKT) into buffer buf (linear LDS dest = lane*16B)
  auto stage = [&](int buf, int kk) {
    if constexpr (BKT == 32) {
      gload_lds16(aptr0 + kk, &sAm[buf][wave * 512]);
      gload_lds16(aptr1 + kk, &sAm[buf][2048 + wave * 512]);
      gload_lds16(wptr0 + kk, &sBm[buf][wave * 512]);
      gload_lds16(wptr1 + kk, &sBm[buf][2048 + wave * 512]);
    } else {
      // BKT=64: 8 threads/row (128 B), 4 passes of 32 rows; source
      // pre-swizzled so content(L) = src[row][ (L&127) ^ ((row&7)<<4) ]
      #pragma unroll
      for (int p = 0; p < 4; ++p) {
        const int row = p * 32 + (tid >> 3);
        const int xb  = ((tid & 7) << 4) ^ ((row & 7) << 4);
        gload_lds16((const bf16*)((const char*)(A + (size_t)(m0 + row) * K + kk) + xb),
                    &sAm[buf][p * 2048 + wave * 512]);
        gload_lds16((const bf16*)((const char*)(W + (size_t)(n0 + row) * K + kk) + xb),
                    &sBm[buf][p * 2048 + wave * 512]);
      }
    }
  };

  stage(0, 0);
  __syncthreads();               // prologue drain: buf0 resident
  int cur = 0;

  for (int kk = 0; kk < K; kk += BKT) {
    if (kk + BKT < K) stage(cur ^ 1, kk + BKT);   // prefetch next slice
    if constexpr (BKT == 32) {
      frag8 af[4], bfr[4];
      #pragma unroll
      for (int t = 0; t < 4; ++t) {
        af[t]  = *(const frag8*)&sAm[cur][(wm + t * 16 + l15) * 32 + quad * 8];
        bfr[t] = *(const frag8*)&sBm[cur][(wn + t * 16 + l15) * 32 + quad * 8];
      }
      #pragma unroll
      for (int mi = 0; mi < 4; ++mi)
        #pragma unroll
        for (int ni = 0; ni < 4; ++ni)
          acc[mi][ni] = __builtin_amdgcn_mfma_f32_16x16x32_bf16(
              af[mi], bfr[ni], acc[mi][ni], 0, 0, 0);
    } else {
      #pragma unroll
      for (int kf = 0; kf < 2; ++kf) {
        frag8 af[4], bfr[4];
        #pragma unroll
        for (int t = 0; t < 4; ++t) {
          const int ra = wm + t * 16 + l15;
          af[t] = *(const frag8*)((const char*)&sAm[cur][0] +
                    ra * 128 + ((kf * 64 + quad * 16) ^ ((ra & 7) << 4)));
          const int rb = wn + t * 16 + l15;
          bfr[t] = *(const frag8*)((const char*)&sBm[cur][0] +
                    rb * 128 + ((kf * 64 + quad * 16) ^ ((rb & 7) << 4)));
        }
        #pragma unroll
        for (int mi = 0; mi < 4; ++mi)
          #pragma unroll
          for (int ni = 0; ni < 4; ++ni)
            acc[mi][ni] = __builtin_amdgcn_mfma_f32_16x16x32_bf16(
                af[mi], bfr[ni], acc[mi][ni], 0, 0, 0);
      }
    }
    __syncthreads();   // drains vmcnt (next slice landed) + lgkm (reads done)
    cur ^= 1;
  }
  // all waves are past their LDS reads here: shared mem is reusable.

  if (mode == EP_KV && n0 >= 1024) {
    // ---- V half: LDS-transposed coalesced epilogue (BKT=32 only) ----
    short* smem = &sAm[0][0];   // 16384 shorts of scratch
    #pragma unroll
    for (int mi = 0; mi < 4; ++mi) {
      #pragma unroll
      for (int reg = 0; reg < 4; ++reg) {
        const int rowl = wm + mi * 16 + quad * 4 + reg;
        const int bbl  = rowl & 7;
        const int tl   = rowl >> 3;
        #pragma unroll
        for (int ni = 0; ni < 4; ++ni) {
          const int coll = wn + ni * 16 + l15;          // 0..127
          const int hn2  = coll >> 6;
          const int d    = coll & 63;
          const int rowid = (bbl * 2 + hn2) * 64 + d;
          smem[tl * 1024 + (rowid ^ (tl << 1))] =
              (short)bfbits(acc[mi][ni][reg]);
        }
      }
    }
    __syncthreads();
    // read phase: each thread emits 4 vT rows (16 t each) as 2x16B stores
    const int hnb = (n0 >> 6) - 16;        // head base for this block
    const int t0  = m0 >> 3;
    #pragma unroll
    for (int p = 0; p < 4; ++p) {
      const int r   = p * 256 + tid;       // rowid 0..1023
      const int bbl = r >> 7;
      const int hn2 = (r >> 6) & 1;
      const int d   = r & 63;
      unsigned short tmp[16];
      #pragma unroll
      for (int tl = 0; tl < 16; ++tl)
        tmp[tl] = (unsigned short)smem[tl * 1024 + (r ^ (tl << 1))];
      bf16* dst = vto + ((size_t)(bbl * 16 + hnb + hn2) * 64 + d) * 1024 + t0;
      *(frag8*)dst       = *(const frag8*)&tmp[0];
      *(frag8*)(dst + 8) = *(const frag8*)&tmp[8];
    }
    return;
  }

  #pragma unroll
  for (int mi = 0; mi < 4; ++mi) {
    #pragma unroll
    for (int reg = 0; reg < 4; ++reg) {
      const int rowl = wm + mi * 16 + quad * 4 + reg;
      const int row  = m0 + rowl;
      if (mode == EP_PLAIN) {
        bf16* orow = out + (size_t)row * N;
        const TRES* rrow = res ? res + (size_t)row * N : nullptr;
        #pragma unroll
        for (int ni = 0; ni < 4; ++ni) {
          const int col = n0 + wn + ni * 16 + l15;
          float v = acc[mi][ni][reg];
          if (bias) v += bias[col];
          if (relu) v = fmaxf(v, 0.f);
          if (rrow) v += tof(rrow[col]);
          orow[col] = f2bf(v);
        }
      } else if (mode == EP_KV) {
        // K half (n0 < 1024): direct stores, 32B/quad chunks
        const int t = row >> 3, bb = row & 7;
        #pragma unroll
        for (int ni = 0; ni < 4; ++ni) {
          const int col = n0 + wn + ni * 16 + l15;
          const int hn = col >> 6, d = col & 63;
          kbo[((size_t)(bb * 16 + hn) * 1024 + t) * 64 + d] =
              f2bf(acc[mi][ni][reg]);
        }
      } else if (mode == EP_Q) {
        // rows are cat rows 4096.. -> t = 512 + row>>3, tq = row>>3
        const int tq = row >> 3, bb = row & 7;
        #pragma unroll
        for (int ni = 0; ni < 4; ++ni) {
          const int col = n0 + wn + ni * 16 + l15;  // 0..1023
          const int hn = col >> 6, d = col & 63;
          const float v = acc[mi][ni][reg];
          const size_t idx = ((size_t)(bb * 16 + hn) * 512 + tq) * 64 + d;
          qwb[idx] = f2bf(v + rwbias[col]);
          qrb[idx] = f2bf(v + rrbias[col]);
        }
      } else { // EP_RK
        #pragma unroll
        for (int ni = 0; ni < 4; ++ni) {
          const int col = n0 + wn + ni * 16 + l15;
          const int hn = col >> 6, d = col & 63;
          qwb[((size_t)hn * 1024 + row) * 64 + d] = f2bf(acc[mi][ni][reg]);
        }
      }
    }
  }
}

// Fused MFMA attention v10: DS-pipe diet, allocation-clean (R10: 97 -> <94us;
// DS ops/wave-tile ~98 -> ~54 via dedup'd shuffles + DPP reduces).
__global__ __launch_bounds__(256, 4)
void fattn(const bf16* __restrict__ qw, const bf16* __restrict__ qr,
           const bf16* __restrict__ kb, const bf16* __restrict__ vT,
           const bf16* __restrict__ rk, bf16* __restrict__ avec)
{
  __shared__ __align__(16) short sK[4096];   // 64 j x 64 d bf16, swizzled (8 KB)
  __shared__ __align__(16) short sV[4096];   // 64 d x 64 j bf16, swizzled (8 KB)
  __shared__ __align__(16) unsigned short p_lds[4][16][64]; // 8 KB, XOR layout
  const int tid  = threadIdx.x;
  const int wave = tid >> 6, lane = tid & 63;
  const int quad = lane >> 4, l15 = lane & 15;
  // XCD-locality decode: bid = r + 8*(phi + 16*it), pair = r + 8*phi
  const int bid = blockIdx.x;
  const int r_  = bid & 7;
  const int s_  = bid >> 3;
  const int phi = s_ & 15;
  const int it  = s_ >> 4;            // i-tile 0..7
  const int pr  = r_ + 8 * phi;       // (h,b) pair 0..127
  const int h   = pr & 15;
  const int b   = pr >> 4;
  const int i0  = it * 64;
  const int iw  = i0 + wave * 16;
  const size_t bh = (size_t)b * 16 + h;
  const bf16* kp = kb + bh * 1024 * 64;
  const bf16* vp = vT + bh * 64 * 1024;
  const bf16* rp = rk + (size_t)h * 1024 * 64;

  frag8 aqw[2], aqr[2];
  {
    const bf16* r0 = qw + (bh * 512 + iw + l15) * 64 + quad * 8;
    aqw[0] = *(const frag8*)r0;
    aqw[1] = *(const frag8*)(r0 + 32);
    const bf16* r1 = qr + (bh * 512 + iw + l15) * 64 + quad * 8;
    aqr[0] = *(const frag8*)r1;
    aqr[1] = *(const frag8*)(r1 + 32);
  }

  f32x4 accO[4] = {};
  float m_run[4], l_run[4];
  #pragma unroll
  for (int rg = 0; rg < 4; ++rg) { m_run[rg] = -INFINITY; l_run[rg] = 0.f; }

  // block-uniform step count (i_last = i0+63); low waves' extra tiles are
  // fully masked (s=-inf -> pv=0 -> no contribution)
  const int nsteps = ((i0 + 63 + 512) >> 6) + 1;
  const int offb   = 15 + l15 - quad * 4;

  // stage j-tile [j0s, j0s+64) of K and V into sK/sV (8 KB each).
  // Linear LDS write (gload_lds, 2 chunks of 4 KB), inverse-swizzled source:
  //   content(byte Lb) = src[Lb ^ ((row&7)<<4)], row = Lb>>7 (128 B rows)
  auto stage = [&](int j0s) {
    #pragma unroll
    for (int c = 0; c < 2; ++c) {
      const int Lb = c * 4096 + tid * 16;
      const int r  = Lb >> 7;            // j-row (K) / d-row (V), 0..63
      const int xb = (Lb & 127) ^ ((r & 7) << 4);
      short* dK = (short*)((char*)sK + (c * 4096 + wave * 1024));
      short* dV = (short*)((char*)sV + (c * 4096 + wave * 1024));
      gload_lds16((const bf16*)((const char*)kp + ((size_t)j0s + r) * 128 + xb), dK);
      gload_lds16((const bf16*)((const char*)vp + (size_t)r * 2048 + (size_t)j0s * 2 + xb), dV);
    }
  };
  stage(0);

  for (int jt = 0; jt < nsteps; ++jt) {
    const int j0 = jt << 6;
    // ---- BD first: global rk loads (L2-resident) overlap K/V staging ----
    const int pbase = 496 + j0 - iw;
    f32x4 bsub[5];
    #pragma unroll
    for (int ns = 0; ns < 5; ++ns) {
      const int prow = min(pbase + ns * 16 + l15, 1023);
      const bf16* rrow = rp + (size_t)prow * 64 + quad * 8;
      frag8 br0 = *(const frag8*)rrow;
      frag8 br1 = *(const frag8*)(rrow + 32);
      f32x4 z = {};
      z = __builtin_amdgcn_mfma_f32_16x16x32_bf16(aqr[0], br0, z, 0,0,0);
      bsub[ns] = __builtin_amdgcn_mfma_f32_16x16x32_bf16(aqr[1], br1, z, 0,0,0);
    }
    __syncthreads();   // sK/sV for this tile are resident
    // ---- AC scores from sK (swizzled ds_read_b128) ----
    f32x4 accS[4] = {};
    #pragma unroll
    for (int ns = 0; ns < 4; ++ns) {
      const int row = ns * 16 + l15;
      const int sw  = (row & 7) << 4;
      frag8 bk0 = *(const frag8*)((const char*)sK + ((row * 128 + quad * 16) ^ sw));
      frag8 bk1 = *(const frag8*)((const char*)sK + ((row * 128 + 64 + quad * 16) ^ sw));
      accS[ns] = __builtin_amdgcn_mfma_f32_16x16x32_bf16(aqw[0], bk0, accS[ns], 0,0,0);
      accS[ns] = __builtin_amdgcn_mfma_f32_16x16x32_bf16(aqw[1], bk1, accS[ns], 0,0,0);
    }
    // ---- shift (dedup'd bpermutes, NAMED scalars) + combine + mask + max ----
    float tmax[4];
    #pragma unroll
    for (int rg = 0; rg < 4; ++rg) {
      const int o    = offb - rg;                 // [0,30]
      const int srcl = (quad << 4) | (o & 15);
      const float s0 = __shfl(bsub[0][rg], srcl, 64);
      const float s1 = __shfl(bsub[1][rg], srcl, 64);
      const float s2 = __shfl(bsub[2][rg], srcl, 64);
      const float s3 = __shfl(bsub[3][rg], srcl, 64);
      const float s4 = __shfl(bsub[4][rg], srcl, 64);
      const bool hi  = (o & 16) != 0;
      const float bd0 = hi ? s1 : s0;
      const float bd1 = hi ? s2 : s1;
      const float bd2 = hi ? s3 : s2;
      const float bd3 = hi ? s4 : s3;
      const int jb   = j0 + l15;
      const int lim  = iw + quad * 4 + rg + 512;
      float v0 = (accS[0][rg] + bd0) * 0.125f;
      float v1 = (accS[1][rg] + bd1) * 0.125f;
      float v2 = (accS[2][rg] + bd2) * 0.125f;
      float v3 = (accS[3][rg] + bd3) * 0.125f;
      v0 = (jb      > lim) ? -INFINITY : v0;
      v1 = (jb + 16 > lim) ? -INFINITY : v1;
      v2 = (jb + 32 > lim) ? -INFINITY : v2;
      v3 = (jb + 48 > lim) ? -INFINITY : v3;
      accS[0][rg] = v0; accS[1][rg] = v1; accS[2][rg] = v2; accS[3][rg] = v3;
      tmax[rg] = rowmax16(fmaxf(fmaxf(v0, v1), fmaxf(v2, v3)));
    }
    // ---- online softmax update (tsum via DPP row-sum, no DS reduce) ----
    float alpha[4], tsum[4] = {0.f, 0.f, 0.f, 0.f};
    #pragma unroll
    for (int rg = 0; rg < 4; ++rg) {
      const float nm = fmaxf(m_run[rg], tmax[rg]);
      alpha[rg] = __expf(m_run[rg] - nm);
      m_run[rg] = nm;
    }
    #pragma unroll
    for (int ns = 0; ns < 4; ++ns)
      #pragma unroll
      for (int rg = 0; rg < 4; ++rg) {
        const int rl = quad * 4 + rg;
        const float pv = __expf(accS[ns][rg] - m_run[rg]);
        tsum[rg] += pv;
        // XOR-compacted p_lds write (16B-granular, matches frag8 read)
        *(unsigned short*)((char*)&p_lds[wave][rl][0] +
            (((ns * 16 + l15) * 2) ^ ((rl & 7) << 4))) = bfbits(pv);
      }
    #pragma unroll
    for (int rg = 0; rg < 4; ++rg) {
      l_run[rg] = l_run[rg] * alpha[rg] + rowsum16(tsum[rg]);
      #pragma unroll
      for (int nd = 0; nd < 4; ++nd)
        accO[nd][rg] *= alpha[rg];
    }
    __builtin_amdgcn_wave_barrier();
    // ---- PV from sV (swizzled ds_read_b128) ----
    #pragma unroll
    for (int ks = 0; ks < 2; ++ks) {
      frag8 ap = *(const frag8*)((const char*)&p_lds[wave][l15][0] +
                  ((ks * 64 + quad * 16) ^ ((l15 & 7) << 4)));
      #pragma unroll
      for (int nd = 0; nd < 4; ++nd) {
        const int d = nd * 16 + l15;
        frag8 bv = *(const frag8*)((const char*)sV +
                    ((d * 128 + ks * 64 + quad * 16) ^ ((d & 7) << 4)));
        accO[nd] = __builtin_amdgcn_mfma_f32_16x16x32_bf16(ap, bv, accO[nd], 0,0,0);
      }
    }
    __builtin_amdgcn_wave_barrier();
    __syncthreads();   // all waves done reading sK/sV
    if (jt + 1 < nsteps) stage((jt + 1) << 6);
  }

  #pragma unroll
  for (int rg = 0; rg < 4; ++rg) {
    const int i = iw + quad * 4 + rg;
    const float inv = 1.f / l_run[rg];
    #pragma unroll
    for (int nd = 0; nd < 4; ++nd) {
      const int d = nd * 16 + l15;
      avec[((size_t)i * 8 + b) * 1024 + h * 64 + d] = f2bf(accO[nd][rg] * inv);
    }
  }
}

// row LayerNorm over 1024 cols; one block per row.
template<typename TOUT>
__global__ __launch_bounds__(256)
void ln_kernel(const bf16* __restrict__ x, const float* __restrict__ g,
               const float* __restrict__ be, TOUT* __restrict__ out)
{
  __shared__ float red0[4];
  __shared__ float red1[4];
  const int row = blockIdx.x;
  const int tid = threadIdx.x;
  const bf16* xr = x + (size_t)row * 1024;
  ushort4 u = *(const ushort4*)(xr + (tid << 2));
  const float v0 = u16f(u.x), v1 = u16f(u.y), v2 = u16f(u.z), v3 = u16f(u.w);
  float sum = v0 + v1 + v2 + v3;
  #pragma unroll
  for (int off = 1; off < 64; off <<= 1) sum += __shfl_xor(sum, off, 64);
  if ((tid & 63) == 0) red0[tid >> 6] = sum;
  __syncthreads();
  const float mu = (red0[0] + red0[1] + red0[2] + red0[3]) * (1.f / 1024.f);
  const float d0 = v0 - mu, d1 = v1 - mu, d2 = v2 - mu, d3 = v3 - mu;
  float sq = d0*d0 + d1*d1 + d2*d2 + d3*d3;
  #pragma unroll
  for (int off = 1; off < 64; off <<= 1) sq += __shfl_xor(sq, off, 64);
  if ((tid & 63) == 0) red1[tid >> 6] = sq;
  __syncthreads();
  const float var = (red1[0] + red1[1] + red1[2] + red1[3]) * (1.f / 1024.f);
  const float inv = 1.f / sqrtf(var + 1e-5f);
  const int c = tid << 2;
  float4 ug = *(const float4*)(g + c);
  float4 ub = *(const float4*)(be + c);
  TOUT* orow = out + (size_t)row * 1024;
  orow[c+0] = (TOUT)(d0 * inv * ug.x + ub.x);
  orow[c+1] = (TOUT)(d1 * inv * ug.y + ub.y);
  orow[c+2] = (TOUT)(d2 * inv * ug.z + ub.z);
  orow[c+3] = (TOUT)(d3 * inv * ug.w + ub.w);
}

extern "C" void kernel_launch(void* const* d_in, const int* in_sizes, int n_in,
                              void* d_out, int out_size, void* d_ws, size_t ws_size,
                              hipStream_t stream)
{
  const float* w    = (const float*)d_in[0];
  const float* r    = (const float*)d_in[1];
  const float* rwb  = (const float*)d_in[2];
  const float* rrb  = (const float*)d_in[3];
  const float* mems = (const float*)d_in[4];
  // d_in[5] = attn_mask: deterministic (j > i + 512), computed in-kernel
  const float* Wqkv = (const float*)d_in[6];
  const float* Wr   = (const float*)d_in[7];
  const float* Wo   = (const float*)d_in[8];
  const float* ln1g = (const float*)d_in[9];
  const float* ln1b = (const float*)d_in[10];
  const float* W1   = (const float*)d_in[11];
  const float* b1   = (const float*)d_in[12];
  const float* W2   = (const float*)d_in[13];
  const float* b2   = (const float*)d_in[14];
  const float* ln2g = (const float*)d_in[15];
  const float* ln2b = (const float*)d_in[16];

  // Workspace (bf16), liveness-aliased, peak 94 MiB (layout unchanged from R5)
  const size_t MB = 1u << 20;
  char* p = (char*)d_ws;
  bf16* catb  = (bf16*)(p +  0 * MB);
  bf16* wqkvb = (bf16*)(p + 16 * MB);
  bf16* wrb   = (bf16*)(p + 22 * MB);
  bf16* wob   = (bf16*)(p + 24 * MB);
  bf16* w1b   = (bf16*)(p + 26 * MB);
  bf16* w2b   = (bf16*)(p + 34 * MB);
  bf16* qwbuf = (bf16*)(p + 42 * MB);
  bf16* qrbuf = (bf16*)(p + 50 * MB);
  bf16* kbuf  = (bf16*)(p + 58 * MB);
  bf16* vTbuf = (bf16*)(p + 74 * MB);
  bf16* rkbuf = (bf16*)(p + 90 * MB);
  bf16* rb    = (bf16*)(p + 92 * MB);
  bf16* avec  = (bf16*)(p +  0 * MB);
  bf16* x1    = (bf16*)(p +  8 * MB);
  bf16* o1    = (bf16*)(p + 42 * MB);
  bf16* x2    = (bf16*)(p + 50 * MB);
  bf16* h     = (bf16*)(p + 58 * MB);

  dim3 blk(256);
  // 0. fp32 -> bf16 converts (one batched launch)
  {
    CvtArgs a;
    const int n4w = (4096 * 1024) / 4, n4r = (1024 * 1024) / 4,
              n4qkv = (3072 * 1024) / 4;
    a.src[0] = mems; a.dst[0] = catb;                        int n0_ = n4w;
    a.src[1] = w;    a.dst[1] = catb + (size_t)4096 * 1024;  int n1_ = n4w;
    a.src[2] = r;    a.dst[2] = rb;                          int n2_ = n4r;
    a.src[3] = Wqkv; a.dst[3] = wqkvb;                       int n3_ = n4qkv;
    a.src[4] = Wr;   a.dst[4] = wrb;                         int n4_ = n4r;
    a.src[5] = Wo;   a.dst[5] = wob;                         int n5_ = n4r;
    a.src[6] = W1;   a.dst[6] = w1b;                         int n6_ = n4w;
    a.src[7] = W2;   a.dst[7] = w2b;                         int n7_ = n4w;
    const int ns_[8] = {n0_, n1_, n2_, n3_, n4_, n5_, n6_, n7_};
    a.cum[0] = 0;
    for (int s2 = 0; s2 < 8; ++s2) a.cum[s2 + 1] = a.cum[s2] + ns_[s2];
    cvt8<<<dim3((a.cum[8] + 255) / 256), blk, 0, stream>>>(a);
  }

  // 1a. K/V projection: cat @ Wqkv[1024:3072]^T -> kb (direct) + vT (LDS-coalesced)
  mgemm<float, 32><<<dim3(16, 64), blk, 0, stream>>>(catb, wqkvb + (size_t)1024 * 1024,
        nullptr, (const float*)nullptr, nullptr, nullptr, nullptr, kbuf, vTbuf,
        nullptr, nullptr, 8192, 2048, 1024, EP_KV, 0);
  // 1b. Q projection: only rows t>=512 (cat rows 4096..8191), biases fused
  mgemm<float, 64><<<dim3(8, 32), blk, 0, stream>>>(catb + (size_t)4096 * 1024, wqkvb,
        nullptr, (const float*)nullptr, nullptr, qwbuf, qrbuf, nullptr, nullptr,
        rwb, rrb, 4096, 1024, 1024, EP_Q, 0);
  // 2. rk = r @ Wr^T -> (h,p,d)
  mgemm<float, 64><<<dim3(8, 8), blk, 0, stream>>>(rb, wrb, nullptr, (const float*)nullptr,
        nullptr, rkbuf, nullptr, nullptr, nullptr, nullptr, nullptr,
        1024, 1024, 1024, EP_RK, 0);
  // 3. fused MFMA attention -> avec (1024 blocks, XCD-swizzled, K/V LDS-staged)
  fattn<<<dim3(1024), blk, 0, stream>>>(qwbuf, qrbuf, kbuf, vTbuf, rkbuf, avec);
  // 4. x1 = w + avec @ Wo^T
  mgemm<float, 64><<<dim3(8, 32), blk, 0, stream>>>(avec, wob, nullptr, w,
        x1, nullptr, nullptr, nullptr, nullptr, nullptr, nullptr,
        4096, 1024, 1024, EP_PLAIN, 0);
  // 5. out1 = LN(x1)
  ln_kernel<bf16><<<dim3(4096), blk, 0, stream>>>(x1, ln1g, ln1b, o1);
  // 6. h = relu(out1 @ W1^T + b1)
  mgemm<float, 32><<<dim3(32, 32), blk, 0, stream>>>(o1, w1b, b1, (const float*)nullptr,
        h, nullptr, nullptr, nullptr, nullptr, nullptr, nullptr,
        4096, 4096, 1024, EP_PLAIN, 1);
  // 7. x2 = out1 + h @ W2^T + b2
  mgemm<bf16, 64><<<dim3(8, 32), blk, 0, stream>>>(h, w2b, b2, o1,
        x2, nullptr, nullptr, nullptr, nullptr, nullptr, nullptr,
        4096, 1024, 4096, EP_PLAIN, 0);
  // 8. out = LN(x2) -> fp32
  ln_kernel<float><<<dim3(4096), blk, 0, stream>>>(x2, ln2g, ln2b, (float*)d_out);
}

// Round 12
// 536.139 us; speedup vs baseline: 1.0030x; 1.0030x over previous
//
#include <hip/hip_runtime.h>
#include <hip/hip_bf16.h>

typedef __hip_bfloat16 bf16;

typedef __attribute__((ext_vector_type(8))) short frag8;
typedef __attribute__((ext_vector_type(4))) float f32x4;

__device__ __forceinline__ bf16 f2bf(float f) { return __float2bfloat16(f); }

__device__ __forceinline__ float u16f(unsigned short u) {
  union { unsigned int i; float f; } c; c.i = ((unsigned int)u) << 16; return c.f;
}
__device__ __forceinline__ unsigned short bfbits(float f) {
  union { bf16 b; unsigned short u; } c; c.b = __float2bfloat16(f); return c.u;
}
__device__ __forceinline__ float tof(float x) { return x; }
__device__ __forceinline__ float tof(bf16 x)  { return __bfloat162float(x); }

// async 16B global->LDS copy (m97 pattern)
__device__ __forceinline__ void gload_lds16(const bf16* g, short* l) {
  __builtin_amdgcn_global_load_lds(
      (const __attribute__((address_space(1))) void*)g,
      (__attribute__((address_space(3))) void*)l, 16, 0, 0);
}

// VALU-pipe cross-lane reduce within each 16-lane row (DPP, no DS ops).
// Transient temps only -- no persistent register cost (R8/R9 lessons).
template<int CTRL>
__device__ __forceinline__ float dppmax(float x) {
  return fmaxf(x, __int_as_float(__builtin_amdgcn_update_dpp(
      0, __float_as_int(x), CTRL, 0xF, 0xF, true)));
}
__device__ __forceinline__ float rowmax16(float x) {
  x = dppmax<0x128>(x);  // row_ror:8
  x = dppmax<0x124>(x);  // row_ror:4
  x = dppmax<0x4E>(x);   // quad_perm {2,3,0,1} = xor2
  x = dppmax<0xB1>(x);   // quad_perm {1,0,3,2} = xor1
  return x;
}
template<int CTRL>
__device__ __forceinline__ float dppadd(float x) {
  return x + __int_as_float(__builtin_amdgcn_update_dpp(
      0, __float_as_int(x), CTRL, 0xF, 0xF, true));
}
__device__ __forceinline__ float rowsum16(float x) {
  x = dppadd<0x128>(x);
  x = dppadd<0x124>(x);
  x = dppadd<0x4E>(x);
  x = dppadd<0xB1>(x);
  return x;
}

#define EP_PLAIN 0
#define EP_RK    2
#define EP_Q     3
#define EP_KV    4

// batched fp32 -> bf16 convert: 8 segments in one launch
struct CvtArgs {
  const float* src[8];
  bf16* dst[8];
  int cum[9];          // cumulative n4 boundaries
};
__global__ __launch_bounds__(256)
void cvt8(CvtArgs a)
{
  const int i = blockIdx.x * 256 + threadIdx.x;
  if (i >= a.cum[8]) return;
  int seg = 7;
  #pragma unroll
  for (int s2 = 6; s2 >= 0; --s2) if (i < a.cum[s2 + 1]) seg = s2;
  const int o = i - a.cum[seg];
  float4 v = ((const float4*)a.src[seg])[o];
  ushort4 u;
  u.x = bfbits(v.x); u.y = bfbits(v.y); u.z = bfbits(v.z); u.w = bfbits(v.w);
  ((ushort4*)a.dst[seg])[o] = u;
}

// MFMA GEMM: C[M,N] = A[M,K] @ W[N,K]^T, bf16 in, fp32 accum.
// 128x128 tile, 4 waves (2x2), double-buffered stage-ahead (R4).
// R12: XCD-chunked 1D grid. R11 counters: FF2 conflicts 4.19M->0 and drains
// halved yet dur unchanged at 94us = FETCH(139.4MB)/1.5TB/s -- fetch-bound.
// Ideal footprint is ~48MB; the 3x L2-miss amplification comes from the
// default mapping (grid(8,32), x fastest -> XCD x%8 owns one N-col and ALL
// 32 M-rows -> every XCD streams the whole 32MB A). Fix: 1D grid, decode
// xcd = bid&7 (m09 round-robin), each XCD gets a CM x CN chunk of the
// block grid minimizing distinct panels/XCD ((gm/CM)*(gn/CN)=8);
// within-chunk N-fastest so co-resident blocks share A panels.
// Pure perf heuristic: wrong mapping only costs speed (G16).
template<typename TRES, int BKT>
__global__ __launch_bounds__(256)
void mgemm(const bf16* __restrict__ A, const bf16* __restrict__ W,
           const float* __restrict__ bias, const TRES* __restrict__ res,
           bf16* __restrict__ out,
           bf16* __restrict__ qwb, bf16* __restrict__ qrb,
           bf16* __restrict__ kbo, bf16* __restrict__ vto,
           const float* __restrict__ rwbias, const float* __restrict__ rrbias,
           int M, int N, int K, int mode, int relu, int gn, int CM, int CN)
{
  __shared__ __align__(16) short sAm[2][128 * BKT];
  __shared__ __align__(16) short sBm[2][128 * BKT];
  const int tid  = threadIdx.x;
  const int lane = tid & 63;
  const int wave = tid >> 6;
  const int quad = lane >> 4;
  const int l15  = lane & 15;
  // XCD-chunked decode: xcd owns chunk (chy, chx) of CMxCN blocks
  const int xcd = blockIdx.x & 7;
  const int k_  = blockIdx.x >> 3;
  const int ncx = gn / CN;
  const int chy = xcd / ncx;
  const int chx = xcd - chy * ncx;
  const int m0 = (chy * CM + k_ / CN) * 128;
  const int n0 = (chx * CN + (k_ % CN)) * 128;
  const int wm = (wave >> 1) * 64;
  const int wn = (wave & 1) * 64;

  const int lr = tid >> 2;
  const int lc = (tid & 3) << 3;

  const bf16* aptr0 = A + (size_t)(m0 + lr) * K + lc;
  const bf16* aptr1 = aptr0 + (size_t)64 * K;
  const bf16* wptr0 = W + (size_t)(n0 + lr) * K + lc;
  const bf16* wptr1 = wptr0 + (size_t)64 * K;

  f32x4 acc[4][4] = {};

  // stage K-slice [kk,kk+BKT) into buffer buf (linear LDS dest = lane*16B)
  auto stage = [&](int buf, int kk) {
    if constexpr (BKT == 32) {
      gload_lds16(aptr0 + kk, &sAm[buf][wave * 512]);
      gload_lds16(aptr1 + kk, &sAm[buf][2048 + wave * 512]);
      gload_lds16(wptr0 + kk, &sBm[buf][wave * 512]);
      gload_lds16(wptr1 + kk, &sBm[buf][2048 + wave * 512]);
    } else {
      // BKT=64: 8 threads/row (128 B), 4 passes of 32 rows; source
      // pre-swizzled so content(L) = src[row][ (L&127) ^ ((row&7)<<4) ]
      #pragma unroll
      for (int p = 0; p < 4; ++p) {
        const int row = p * 32 + (tid >> 3);
        const int xb  = ((tid & 7) << 4) ^ ((row & 7) << 4);
        gload_lds16((const bf16*)((const char*)(A + (size_t)(m0 + row) * K + kk) + xb),
                    &sAm[buf][p * 2048 + wave * 512]);
        gload_lds16((const bf16*)((const char*)(W + (size_t)(n0 + row) * K + kk) + xb),
                    &sBm[buf][p * 2048 + wave * 512]);
      }
    }
  };

  stage(0, 0);
  __syncthreads();               // prologue drain: buf0 resident
  int cur = 0;

  for (int kk = 0; kk < K; kk += BKT) {
    if (kk + BKT < K) stage(cur ^ 1, kk + BKT);   // prefetch next slice
    if constexpr (BKT == 32) {
      frag8 af[4], bfr[4];
      #pragma unroll
      for (int t = 0; t < 4; ++t) {
        af[t]  = *(const frag8*)&sAm[cur][(wm + t * 16 + l15) * 32 + quad * 8];
        bfr[t] = *(const frag8*)&sBm[cur][(wn + t * 16 + l15) * 32 + quad * 8];
      }
      #pragma unroll
      for (int mi = 0; mi < 4; ++mi)
        #pragma unroll
        for (int ni = 0; ni < 4; ++ni)
          acc[mi][ni] = __builtin_amdgcn_mfma_f32_16x16x32_bf16(
              af[mi], bfr[ni], acc[mi][ni], 0, 0, 0);
    } else {
      #pragma unroll
      for (int kf = 0; kf < 2; ++kf) {
        frag8 af[4], bfr[4];
        #pragma unroll
        for (int t = 0; t < 4; ++t) {
          const int ra = wm + t * 16 + l15;
          af[t] = *(const frag8*)((const char*)&sAm[cur][0] +
                    ra * 128 + ((kf * 64 + quad * 16) ^ ((ra & 7) << 4)));
          const int rb = wn + t * 16 + l15;
          bfr[t] = *(const frag8*)((const char*)&sBm[cur][0] +
                    rb * 128 + ((kf * 64 + quad * 16) ^ ((rb & 7) << 4)));
        }
        #pragma unroll
        for (int mi = 0; mi < 4; ++mi)
          #pragma unroll
          for (int ni = 0; ni < 4; ++ni)
            acc[mi][ni] = __builtin_amdgcn_mfma_f32_16x16x32_bf16(
                af[mi], bfr[ni], acc[mi][ni], 0, 0, 0);
      }
    }
    __syncthreads();   // drains vmcnt (next slice landed) + lgkm (reads done)
    cur ^= 1;
  }
  // all waves are past their LDS reads here: shared mem is reusable.

  if (mode == EP_KV && n0 >= 1024) {
    // ---- V half: LDS-transposed coalesced epilogue (BKT=32 only) ----
    short* smem = &sAm[0][0];   // 16384 shorts of scratch
    #pragma unroll
    for (int mi = 0; mi < 4; ++mi) {
      #pragma unroll
      for (int reg = 0; reg < 4; ++reg) {
        const int rowl = wm + mi * 16 + quad * 4 + reg;
        const int bbl  = rowl & 7;
        const int tl   = rowl >> 3;
        #pragma unroll
        for (int ni = 0; ni < 4; ++ni) {
          const int coll = wn + ni * 16 + l15;          // 0..127
          const int hn2  = coll >> 6;
          const int d    = coll & 63;
          const int rowid = (bbl * 2 + hn2) * 64 + d;
          smem[tl * 1024 + (rowid ^ (tl << 1))] =
              (short)bfbits(acc[mi][ni][reg]);
        }
      }
    }
    __syncthreads();
    // read phase: each thread emits 4 vT rows (16 t each) as 2x16B stores
    const int hnb = (n0 >> 6) - 16;        // head base for this block
    const int t0  = m0 >> 3;
    #pragma unroll
    for (int p = 0; p < 4; ++p) {
      const int r   = p * 256 + tid;       // rowid 0..1023
      const int bbl = r >> 7;
      const int hn2 = (r >> 6) & 1;
      const int d   = r & 63;
      unsigned short tmp[16];
      #pragma unroll
      for (int tl = 0; tl < 16; ++tl)
        tmp[tl] = (unsigned short)smem[tl * 1024 + (r ^ (tl << 1))];
      bf16* dst = vto + ((size_t)(bbl * 16 + hnb + hn2) * 64 + d) * 1024 + t0;
      *(frag8*)dst       = *(const frag8*)&tmp[0];
      *(frag8*)(dst + 8) = *(const frag8*)&tmp[8];
    }
    return;
  }

  #pragma unroll
  for (int mi = 0; mi < 4; ++mi) {
    #pragma unroll
    for (int reg = 0; reg < 4; ++reg) {
      const int rowl = wm + mi * 16 + quad * 4 + reg;
      const int row  = m0 + rowl;
      if (mode == EP_PLAIN) {
        bf16* orow = out + (size_t)row * N;
        const TRES* rrow = res ? res + (size_t)row * N : nullptr;
        #pragma unroll
        for (int ni = 0; ni < 4; ++ni) {
          const int col = n0 + wn + ni * 16 + l15;
          float v = acc[mi][ni][reg];
          if (bias) v += bias[col];
          if (relu) v = fmaxf(v, 0.f);
          if (rrow) v += tof(rrow[col]);
          orow[col] = f2bf(v);
        }
      } else if (mode == EP_KV) {
        // K half (n0 < 1024): direct stores, 32B/quad chunks
        const int t = row >> 3, bb = row & 7;
        #pragma unroll
        for (int ni = 0; ni < 4; ++ni) {
          const int col = n0 + wn + ni * 16 + l15;
          const int hn = col >> 6, d = col & 63;
          kbo[((size_t)(bb * 16 + hn) * 1024 + t) * 64 + d] =
              f2bf(acc[mi][ni][reg]);
        }
      } else if (mode == EP_Q) {
        // rows are cat rows 4096.. -> t = 512 + row>>3, tq = row>>3
        const int tq = row >> 3, bb = row & 7;
        #pragma unroll
        for (int ni = 0; ni < 4; ++ni) {
          const int col = n0 + wn + ni * 16 + l15;  // 0..1023
          const int hn = col >> 6, d = col & 63;
          const float v = acc[mi][ni][reg];
          const size_t idx = ((size_t)(bb * 16 + hn) * 512 + tq) * 64 + d;
          qwb[idx] = f2bf(v + rwbias[col]);
          qrb[idx] = f2bf(v + rrbias[col]);
        }
      } else { // EP_RK
        #pragma unroll
        for (int ni = 0; ni < 4; ++ni) {
          const int col = n0 + wn + ni * 16 + l15;
          const int hn = col >> 6, d = col & 63;
          qwb[((size_t)hn * 1024 + row) * 64 + d] = f2bf(acc[mi][ni][reg]);
        }
      }
    }
  }
}

// Fused MFMA attention v10: DS-pipe diet, allocation-clean (R10: 97 -> <94us;
// DS ops/wave-tile ~98 -> ~54 via dedup'd shuffles + DPP reduces).
__global__ __launch_bounds__(256, 4)
void fattn(const bf16* __restrict__ qw, const bf16* __restrict__ qr,
           const bf16* __restrict__ kb, const bf16* __restrict__ vT,
           const bf16* __restrict__ rk, bf16* __restrict__ avec)
{
  __shared__ __align__(16) short sK[4096];   // 64 j x 64 d bf16, swizzled (8 KB)
  __shared__ __align__(16) short sV[4096];   // 64 d x 64 j bf16, swizzled (8 KB)
  __shared__ __align__(16) unsigned short p_lds[4][16][64]; // 8 KB, XOR layout
  const int tid  = threadIdx.x;
  const int wave = tid >> 6, lane = tid & 63;
  const int quad = lane >> 4, l15 = lane & 15;
  // XCD-locality decode: bid = r + 8*(phi + 16*it), pair = r + 8*phi
  const int bid = blockIdx.x;
  const int r_  = bid & 7;
  const int s_  = bid >> 3;
  const int phi = s_ & 15;
  const int it  = s_ >> 4;            // i-tile 0..7
  const int pr  = r_ + 8 * phi;       // (h,b) pair 0..127
  const int h   = pr & 15;
  const int b   = pr >> 4;
  const int i0  = it * 64;
  const int iw  = i0 + wave * 16;
  const size_t bh = (size_t)b * 16 + h;
  const bf16* kp = kb + bh * 1024 * 64;
  const bf16* vp = vT + bh * 64 * 1024;
  const bf16* rp = rk + (size_t)h * 1024 * 64;

  frag8 aqw[2], aqr[2];
  {
    const bf16* r0 = qw + (bh * 512 + iw + l15) * 64 + quad * 8;
    aqw[0] = *(const frag8*)r0;
    aqw[1] = *(const frag8*)(r0 + 32);
    const bf16* r1 = qr + (bh * 512 + iw + l15) * 64 + quad * 8;
    aqr[0] = *(const frag8*)r1;
    aqr[1] = *(const frag8*)(r1 + 32);
  }

  f32x4 accO[4] = {};
  float m_run[4], l_run[4];
  #pragma unroll
  for (int rg = 0; rg < 4; ++rg) { m_run[rg] = -INFINITY; l_run[rg] = 0.f; }

  // block-uniform step count (i_last = i0+63); low waves' extra tiles are
  // fully masked (s=-inf -> pv=0 -> no contribution)
  const int nsteps = ((i0 + 63 + 512) >> 6) + 1;
  const int offb   = 15 + l15 - quad * 4;

  // stage j-tile [j0s, j0s+64) of K and V into sK/sV (8 KB each).
  // Linear LDS write (gload_lds, 2 chunks of 4 KB), inverse-swizzled source:
  //   content(byte Lb) = src[Lb ^ ((row&7)<<4)], row = Lb>>7 (128 B rows)
  auto stage = [&](int j0s) {
    #pragma unroll
    for (int c = 0; c < 2; ++c) {
      const int Lb = c * 4096 + tid * 16;
      const int r  = Lb >> 7;            // j-row (K) / d-row (V), 0..63
      const int xb = (Lb & 127) ^ ((r & 7) << 4);
      short* dK = (short*)((char*)sK + (c * 4096 + wave * 1024));
      short* dV = (short*)((char*)sV + (c * 4096 + wave * 1024));
      gload_lds16((const bf16*)((const char*)kp + ((size_t)j0s + r) * 128 + xb), dK);
      gload_lds16((const bf16*)((const char*)vp + (size_t)r * 2048 + (size_t)j0s * 2 + xb), dV);
    }
  };
  stage(0);

  for (int jt = 0; jt < nsteps; ++jt) {
    const int j0 = jt << 6;
    // ---- BD first: global rk loads (L2-resident) overlap K/V staging ----
    const int pbase = 496 + j0 - iw;
    f32x4 bsub[5];
    #pragma unroll
    for (int ns = 0; ns < 5; ++ns) {
      const int prow = min(pbase + ns * 16 + l15, 1023);
      const bf16* rrow = rp + (size_t)prow * 64 + quad * 8;
      frag8 br0 = *(const frag8*)rrow;
      frag8 br1 = *(const frag8*)(rrow + 32);
      f32x4 z = {};
      z = __builtin_amdgcn_mfma_f32_16x16x32_bf16(aqr[0], br0, z, 0,0,0);
      bsub[ns] = __builtin_amdgcn_mfma_f32_16x16x32_bf16(aqr[1], br1, z, 0,0,0);
    }
    __syncthreads();   // sK/sV for this tile are resident
    // ---- AC scores from sK (swizzled ds_read_b128) ----
    f32x4 accS[4] = {};
    #pragma unroll
    for (int ns = 0; ns < 4; ++ns) {
      const int row = ns * 16 + l15;
      const int sw  = (row & 7) << 4;
      frag8 bk0 = *(const frag8*)((const char*)sK + ((row * 128 + quad * 16) ^ sw));
      frag8 bk1 = *(const frag8*)((const char*)sK + ((row * 128 + 64 + quad * 16) ^ sw));
      accS[ns] = __builtin_amdgcn_mfma_f32_16x16x32_bf16(aqw[0], bk0, accS[ns], 0,0,0);
      accS[ns] = __builtin_amdgcn_mfma_f32_16x16x32_bf16(aqw[1], bk1, accS[ns], 0,0,0);
    }
    // ---- shift (dedup'd bpermutes, NAMED scalars) + combine + mask + max ----
    float tmax[4];
    #pragma unroll
    for (int rg = 0; rg < 4; ++rg) {
      const int o    = offb - rg;                 // [0,30]
      const int srcl = (quad << 4) | (o & 15);
      const float s0 = __shfl(bsub[0][rg], srcl, 64);
      const float s1 = __shfl(bsub[1][rg], srcl, 64);
      const float s2 = __shfl(bsub[2][rg], srcl, 64);
      const float s3 = __shfl(bsub[3][rg], srcl, 64);
      const float s4 = __shfl(bsub[4][rg], srcl, 64);
      const bool hi  = (o & 16) != 0;
      const float bd0 = hi ? s1 : s0;
      const float bd1 = hi ? s2 : s1;
      const float bd2 = hi ? s3 : s2;
      const float bd3 = hi ? s4 : s3;
      const int jb   = j0 + l15;
      const int lim  = iw + quad * 4 + rg + 512;
      float v0 = (accS[0][rg] + bd0) * 0.125f;
      float v1 = (accS[1][rg] + bd1) * 0.125f;
      float v2 = (accS[2][rg] + bd2) * 0.125f;
      float v3 = (accS[3][rg] + bd3) * 0.125f;
      v0 = (jb      > lim) ? -INFINITY : v0;
      v1 = (jb + 16 > lim) ? -INFINITY : v1;
      v2 = (jb + 32 > lim) ? -INFINITY : v2;
      v3 = (jb + 48 > lim) ? -INFINITY : v3;
      accS[0][rg] = v0; accS[1][rg] = v1; accS[2][rg] = v2; accS[3][rg] = v3;
      tmax[rg] = rowmax16(fmaxf(fmaxf(v0, v1), fmaxf(v2, v3)));
    }
    // ---- online softmax update (tsum via DPP row-sum, no DS reduce) ----
    float alpha[4], tsum[4] = {0.f, 0.f, 0.f, 0.f};
    #pragma unroll
    for (int rg = 0; rg < 4; ++rg) {
      const float nm = fmaxf(m_run[rg], tmax[rg]);
      alpha[rg] = __expf(m_run[rg] - nm);
      m_run[rg] = nm;
    }
    #pragma unroll
    for (int ns = 0; ns < 4; ++ns)
      #pragma unroll
      for (int rg = 0; rg < 4; ++rg) {
        const int rl = quad * 4 + rg;
        const float pv = __expf(accS[ns][rg] - m_run[rg]);
        tsum[rg] += pv;
        // XOR-compacted p_lds write (16B-granular, matches frag8 read)
        *(unsigned short*)((char*)&p_lds[wave][rl][0] +
            (((ns * 16 + l15) * 2) ^ ((rl & 7) << 4))) = bfbits(pv);
      }
    #pragma unroll
    for (int rg = 0; rg < 4; ++rg) {
      l_run[rg] = l_run[rg] * alpha[rg] + rowsum16(tsum[rg]);
      #pragma unroll
      for (int nd = 0; nd < 4; ++nd)
        accO[nd][rg] *= alpha[rg];
    }
    __builtin_amdgcn_wave_barrier();
    // ---- PV from sV (swizzled ds_read_b128) ----
    #pragma unroll
    for (int ks = 0; ks < 2; ++ks) {
      frag8 ap = *(const frag8*)((const char*)&p_lds[wave][l15][0] +
                  ((ks * 64 + quad * 16) ^ ((l15 & 7) << 4)));
      #pragma unroll
      for (int nd = 0; nd < 4; ++nd) {
        const int d = nd * 16 + l15;
        frag8 bv = *(const frag8*)((const char*)sV +
                    ((d * 128 + ks * 64 + quad * 16) ^ ((d & 7) << 4)));
        accO[nd] = __builtin_amdgcn_mfma_f32_16x16x32_bf16(ap, bv, accO[nd], 0,0,0);
      }
    }
    __builtin_amdgcn_wave_barrier();
    __syncthreads();   // all waves done reading sK/sV
    if (jt + 1 < nsteps) stage((jt + 1) << 6);
  }

  #pragma unroll
  for (int rg = 0; rg < 4; ++rg) {
    const int i = iw + quad * 4 + rg;
    const float inv = 1.f / l_run[rg];
    #pragma unroll
    for (int nd = 0; nd < 4; ++nd) {
      const int d = nd * 16 + l15;
      avec[((size_t)i * 8 + b) * 1024 + h * 64 + d] = f2bf(accO[nd][rg] * inv);
    }
  }
}

// row LayerNorm over 1024 cols; one block per row.
template<typename TOUT>
__global__ __launch_bounds__(256)
void ln_kernel(const bf16* __restrict__ x, const float* __restrict__ g,
               const float* __restrict__ be, TOUT* __restrict__ out)
{
  __shared__ float red0[4];
  __shared__ float red1[4];
  const int row = blockIdx.x;
  const int tid = threadIdx.x;
  const bf16* xr = x + (size_t)row * 1024;
  ushort4 u = *(const ushort4*)(xr + (tid << 2));
  const float v0 = u16f(u.x), v1 = u16f(u.y), v2 = u16f(u.z), v3 = u16f(u.w);
  float sum = v0 + v1 + v2 + v3;
  #pragma unroll
  for (int off = 1; off < 64; off <<= 1) sum += __shfl_xor(sum, off, 64);
  if ((tid & 63) == 0) red0[tid >> 6] = sum;
  __syncthreads();
  const float mu = (red0[0] + red0[1] + red0[2] + red0[3]) * (1.f / 1024.f);
  const float d0 = v0 - mu, d1 = v1 - mu, d2 = v2 - mu, d3 = v3 - mu;
  float sq = d0*d0 + d1*d1 + d2*d2 + d3*d3;
  #pragma unroll
  for (int off = 1; off < 64; off <<= 1) sq += __shfl_xor(sq, off, 64);
  if ((tid & 63) == 0) red1[tid >> 6] = sq;
  __syncthreads();
  const float var = (red1[0] + red1[1] + red1[2] + red1[3]) * (1.f / 1024.f);
  const float inv = 1.f / sqrtf(var + 1e-5f);
  const int c = tid << 2;
  float4 ug = *(const float4*)(g + c);
  float4 ub = *(const float4*)(be + c);
  TOUT* orow = out + (size_t)row * 1024;
  orow[c+0] = (TOUT)(d0 * inv * ug.x + ub.x);
  orow[c+1] = (TOUT)(d1 * inv * ug.y + ub.y);
  orow[c+2] = (TOUT)(d2 * inv * ug.z + ub.z);
  orow[c+3] = (TOUT)(d3 * inv * ug.w + ub.w);
}

extern "C" void kernel_launch(void* const* d_in, const int* in_sizes, int n_in,
                              void* d_out, int out_size, void* d_ws, size_t ws_size,
                              hipStream_t stream)
{
  const float* w    = (const float*)d_in[0];
  const float* r    = (const float*)d_in[1];
  const float* rwb  = (const float*)d_in[2];
  const float* rrb  = (const float*)d_in[3];
  const float* mems = (const float*)d_in[4];
  // d_in[5] = attn_mask: deterministic (j > i + 512), computed in-kernel
  const float* Wqkv = (const float*)d_in[6];
  const float* Wr   = (const float*)d_in[7];
  const float* Wo   = (const float*)d_in[8];
  const float* ln1g = (const float*)d_in[9];
  const float* ln1b = (const float*)d_in[10];
  const float* W1   = (const float*)d_in[11];
  const float* b1   = (const float*)d_in[12];
  const float* W2   = (const float*)d_in[13];
  const float* b2   = (const float*)d_in[14];
  const float* ln2g = (const float*)d_in[15];
  const float* ln2b = (const float*)d_in[16];

  // Workspace (bf16), liveness-aliased, peak 94 MiB (layout unchanged from R5)
  const size_t MB = 1u << 20;
  char* p = (char*)d_ws;
  bf16* catb  = (bf16*)(p +  0 * MB);
  bf16* wqkvb = (bf16*)(p + 16 * MB);
  bf16* wrb   = (bf16*)(p + 22 * MB);
  bf16* wob   = (bf16*)(p + 24 * MB);
  bf16* w1b   = (bf16*)(p + 26 * MB);
  bf16* w2b   = (bf16*)(p + 34 * MB);
  bf16* qwbuf = (bf16*)(p + 42 * MB);
  bf16* qrbuf = (bf16*)(p + 50 * MB);
  bf16* kbuf  = (bf16*)(p + 58 * MB);
  bf16* vTbuf = (bf16*)(p + 74 * MB);
  bf16* rkbuf = (bf16*)(p + 90 * MB);
  bf16* rb    = (bf16*)(p + 92 * MB);
  bf16* avec  = (bf16*)(p +  0 * MB);
  bf16* x1    = (bf16*)(p +  8 * MB);
  bf16* o1    = (bf16*)(p + 42 * MB);
  bf16* x2    = (bf16*)(p + 50 * MB);
  bf16* h     = (bf16*)(p + 58 * MB);

  dim3 blk(256);
  // 0. fp32 -> bf16 converts (one batched launch)
  {
    CvtArgs a;
    const int n4w = (4096 * 1024) / 4, n4r = (1024 * 1024) / 4,
              n4qkv = (3072 * 1024) / 4;
    a.src[0] = mems; a.dst[0] = catb;                        int n0_ = n4w;
    a.src[1] = w;    a.dst[1] = catb + (size_t)4096 * 1024;  int n1_ = n4w;
    a.src[2] = r;    a.dst[2] = rb;                          int n2_ = n4r;
    a.src[3] = Wqkv; a.dst[3] = wqkvb;                       int n3_ = n4qkv;
    a.src[4] = Wr;   a.dst[4] = wrb;                         int n4_ = n4r;
    a.src[5] = Wo;   a.dst[5] = wob;                         int n5_ = n4r;
    a.src[6] = W1;   a.dst[6] = w1b;                         int n6_ = n4w;
    a.src[7] = W2;   a.dst[7] = w2b;                         int n7_ = n4w;
    const int ns_[8] = {n0_, n1_, n2_, n3_, n4_, n5_, n6_, n7_};
    a.cum[0] = 0;
    for (int s2 = 0; s2 < 8; ++s2) a.cum[s2 + 1] = a.cum[s2] + ns_[s2];
    cvt8<<<dim3((a.cum[8] + 255) / 256), blk, 0, stream>>>(a);
  }

  // 1a. K/V projection: cat @ Wqkv[1024:3072]^T -> kb + vT (LDS-coalesced)
  //     gm=64, gn=16; XCD chunk 16M x 8N (4x2 chunks)
  mgemm<float, 32><<<dim3(1024), blk, 0, stream>>>(catb, wqkvb + (size_t)1024 * 1024,
        nullptr, (const float*)nullptr, nullptr, nullptr, nullptr, kbuf, vTbuf,
        nullptr, nullptr, 8192, 2048, 1024, EP_KV, 0, 16, 16, 8);
  // 1b. Q projection: rows t>=512 only; gm=32, gn=8; chunk 4M x 8N (8x1)
  mgemm<float, 64><<<dim3(256), blk, 0, stream>>>(catb + (size_t)4096 * 1024, wqkvb,
        nullptr, (const float*)nullptr, nullptr, qwbuf, qrbuf, nullptr, nullptr,
        rwb, rrb, 4096, 1024, 1024, EP_Q, 0, 8, 4, 8);
  // 2. rk = r @ Wr^T; gm=8, gn=8; chunk 2M x 4N (4x2)
  mgemm<float, 64><<<dim3(64), blk, 0, stream>>>(rb, wrb, nullptr, (const float*)nullptr,
        nullptr, rkbuf, nullptr, nullptr, nullptr, nullptr, nullptr,
        1024, 1024, 1024, EP_RK, 0, 8, 2, 4);
  // 3. fused MFMA attention -> avec (1024 blocks, XCD-swizzled, K/V LDS-staged)
  fattn<<<dim3(1024), blk, 0, stream>>>(qwbuf, qrbuf, kbuf, vTbuf, rkbuf, avec);
  // 4. x1 = w + avec @ Wo^T; gm=32, gn=8; chunk 4M x 8N (8x1)
  mgemm<float, 64><<<dim3(256), blk, 0, stream>>>(avec, wob, nullptr, w,
        x1, nullptr, nullptr, nullptr, nullptr, nullptr, nullptr,
        4096, 1024, 1024, EP_PLAIN, 0, 8, 4, 8);
  // 5. out1 = LN(x1)
  ln_kernel<bf16><<<dim3(4096), blk, 0, stream>>>(x1, ln1g, ln1b, o1);
  // 6. h = relu(out1 @ W1^T + b1); gm=32, gn=32; chunk 8M x 16N (4x2)
  mgemm<float, 32><<<dim3(1024), blk, 0, stream>>>(o1, w1b, b1, (const float*)nullptr,
        h, nullptr, nullptr, nullptr, nullptr, nullptr, nullptr,
        4096, 4096, 1024, EP_PLAIN, 1, 32, 8, 16);
  // 7. x2 = out1 + h @ W2^T + b2; gm=32, gn=8; chunk 4M x 8N (8x1)
  mgemm<bf16, 64><<<dim3(256), blk, 0, stream>>>(h, w2b, b2, o1,
        x2, nullptr, nullptr, nullptr, nullptr, nullptr, nullptr,
        4096, 1024, 4096, EP_PLAIN, 0, 8, 4, 8);
  // 8. out = LN(x2) -> fp32
  ln_kernel<float><<<dim3(4096), blk, 0, stream>>>(x2, ln2g, ln2b, (float*)d_out);
}

// Round 14
// 490.967 us; speedup vs baseline: 1.0953x; 1.0920x over previous
//
#include <hip/hip_runtime.h>
#include <hip/hip_bf16.h>

typedef __hip_bfloat16 bf16;

typedef __attribute__((ext_vector_type(8))) short frag8;
typedef __attribute__((ext_vector_type(4))) float f32x4;

__device__ __forceinline__ bf16 f2bf(float f) { return __float2bfloat16(f); }

__device__ __forceinline__ float u16f(unsigned short u) {
  union { unsigned int i; float f; } c; c.i = ((unsigned int)u) << 16; return c.f;
}
__device__ __forceinline__ unsigned short bfbits(float f) {
  union { bf16 b; unsigned short u; } c; c.b = __float2bfloat16(f); return c.u;
}
__device__ __forceinline__ float tof(float x) { return x; }
__device__ __forceinline__ float tof(bf16 x)  { return __bfloat162float(x); }

// async 16B global->LDS copy (m97 pattern)
__device__ __forceinline__ void gload_lds16(const bf16* g, short* l) {
  __builtin_amdgcn_global_load_lds(
      (const __attribute__((address_space(1))) void*)g,
      (__attribute__((address_space(3))) void*)l, 16, 0, 0);
}

// VALU-pipe cross-lane reduce within each 16-lane row (DPP, no DS ops).
// Transient temps only -- no persistent register cost (R8/R9 lessons).
template<int CTRL>
__device__ __forceinline__ float dppmax(float x) {
  return fmaxf(x, __int_as_float(__builtin_amdgcn_update_dpp(
      0, __float_as_int(x), CTRL, 0xF, 0xF, true)));
}
__device__ __forceinline__ float rowmax16(float x) {
  x = dppmax<0x128>(x);  // row_ror:8
  x = dppmax<0x124>(x);  // row_ror:4
  x = dppmax<0x4E>(x);   // quad_perm {2,3,0,1} = xor2
  x = dppmax<0xB1>(x);   // quad_perm {1,0,3,2} = xor1
  return x;
}
template<int CTRL>
__device__ __forceinline__ float dppadd(float x) {
  return x + __int_as_float(__builtin_amdgcn_update_dpp(
      0, __float_as_int(x), CTRL, 0xF, 0xF, true));
}
__device__ __forceinline__ float rowsum16(float x) {
  x = dppadd<0x128>(x);
  x = dppadd<0x124>(x);
  x = dppadd<0x4E>(x);
  x = dppadd<0xB1>(x);
  return x;
}

#define EP_PLAIN 0
#define EP_RK    2
#define EP_Q     3
#define EP_KV    4
#define EP_PART  5

// batched fp32 -> bf16 convert: 8 segments in one launch
struct CvtArgs {
  const float* src[8];
  bf16* dst[8];
  int cum[9];          // cumulative n4 boundaries
};
__global__ __launch_bounds__(256)
void cvt8(CvtArgs a)
{
  const int i = blockIdx.x * 256 + threadIdx.x;
  if (i >= a.cum[8]) return;
  int seg = 7;
  #pragma unroll
  for (int s2 = 6; s2 >= 0; --s2) if (i < a.cum[s2 + 1]) seg = s2;
  const int o = i - a.cum[seg];
  float4 v = ((const float4*)a.src[seg])[o];
  ushort4 u;
  u.x = bfbits(v.x); u.y = bfbits(v.y); u.z = bfbits(v.z); u.w = bfbits(v.w);
  ((ushort4*)a.dst[seg])[o] = u;
}

// MFMA GEMM: C[M,N] = A[M,K] @ W[N,K]^T, bf16 in, fp32 accum.
// 128x128 tile, 4 waves (2x2), double-buffered stage-ahead (R4),
// XCD-chunked 1D grid (R12: FF2 FETCH 139->53 MB, = ideal).
// R13: split-K (EP_PART). R10-R12 data pins FF2's bound: per-CU staging
// throughput (~9.5 B/cy at 1 block/CU; time = bytes/thru; BKT x2 -> step x2;
// FETCH /2.6 -> no change). Throughput scales with co-resident blocks
// (m97 @4 blocks/CU: ~22 B/cy; FF1 @4: ~4x FF2's rate). Fix for the
// 1-block/CU GEMMs (FF2, Wo): split K into 2 segments (grid 512 = 2
// blocks/CU, SAME total staged bytes), f32 partials, reduction fused into
// the adjacent LayerNorm (ln_red). sblk = blocks per segment; s = K-segment
// index; Ks = row stride (full K), K = per-segment loop length.
template<typename TRES, int BKT>
__global__ __launch_bounds__(256)
void mgemm(const bf16* __restrict__ A, const bf16* __restrict__ W,
           const float* __restrict__ bias, const TRES* __restrict__ res,
           bf16* __restrict__ out, float* __restrict__ pout,
           bf16* __restrict__ qwb, bf16* __restrict__ qrb,
           bf16* __restrict__ kbo, bf16* __restrict__ vto,
           const float* __restrict__ rwbias, const float* __restrict__ rrbias,
           int M, int N, int K, int Ks, int mode, int relu,
           int gn, int CM, int CN, int sblk)
{
  __shared__ __align__(16) short sAm[2][128 * BKT];
  __shared__ __align__(16) short sBm[2][128 * BKT];
  const int tid  = threadIdx.x;
  const int lane = tid & 63;
  const int wave = tid >> 6;
  const int quad = lane >> 4;
  const int l15  = lane & 15;
  // split-K decode, then XCD-chunk decode within the segment
  const int s     = blockIdx.x / sblk;
  const int inner = blockIdx.x - s * sblk;
  const int koff  = s * K;
  const int xcd = inner & 7;
  const int k_  = inner >> 3;
  const int ncx = gn / CN;
  const int chy = xcd / ncx;
  const int chx = xcd - chy * ncx;
  const int m0 = (chy * CM + k_ / CN) * 128;
  const int n0 = (chx * CN + (k_ % CN)) * 128;
  const int wm = (wave >> 1) * 64;
  const int wn = (wave & 1) * 64;

  const int lr = tid >> 2;
  const int lc = (tid & 3) << 3;

  const bf16* aptr0 = A + (size_t)(m0 + lr) * Ks + lc + koff;
  const bf16* aptr1 = aptr0 + (size_t)64 * Ks;
  const bf16* wptr0 = W + (size_t)(n0 + lr) * Ks + lc + koff;
  const bf16* wptr1 = wptr0 + (size_t)64 * Ks;

  f32x4 acc[4][4] = {};

  // stage K-slice [kk,kk+BKT) into buffer buf (linear LDS dest = lane*16B)
  auto stage = [&](int buf, int kk) {
    if constexpr (BKT == 32) {
      gload_lds16(aptr0 + kk, &sAm[buf][wave * 512]);
      gload_lds16(aptr1 + kk, &sAm[buf][2048 + wave * 512]);
      gload_lds16(wptr0 + kk, &sBm[buf][wave * 512]);
      gload_lds16(wptr1 + kk, &sBm[buf][2048 + wave * 512]);
    } else {
      // BKT=64: 8 threads/row (128 B), 4 passes of 32 rows; source
      // pre-swizzled so content(L) = src[row][ (L&127) ^ ((row&7)<<4) ]
      #pragma unroll
      for (int p = 0; p < 4; ++p) {
        const int row = p * 32 + (tid >> 3);
        const int xb  = ((tid & 7) << 4) ^ ((row & 7) << 4);
        gload_lds16((const bf16*)((const char*)(A + (size_t)(m0 + row) * Ks + kk + koff) + xb),
                    &sAm[buf][p * 2048 + wave * 512]);
        gload_lds16((const bf16*)((const char*)(W + (size_t)(n0 + row) * Ks + kk + koff) + xb),
                    &sBm[buf][p * 2048 + wave * 512]);
      }
    }
  };

  stage(0, 0);
  __syncthreads();               // prologue drain: buf0 resident
  int cur = 0;

  for (int kk = 0; kk < K; kk += BKT) {
    if (kk + BKT < K) stage(cur ^ 1, kk + BKT);   // prefetch next slice
    if constexpr (BKT == 32) {
      frag8 af[4], bfr[4];
      #pragma unroll
      for (int t = 0; t < 4; ++t) {
        af[t]  = *(const frag8*)&sAm[cur][(wm + t * 16 + l15) * 32 + quad * 8];
        bfr[t] = *(const frag8*)&sBm[cur][(wn + t * 16 + l15) * 32 + quad * 8];
      }
      #pragma unroll
      for (int mi = 0; mi < 4; ++mi)
        #pragma unroll
        for (int ni = 0; ni < 4; ++ni)
          acc[mi][ni] = __builtin_amdgcn_mfma_f32_16x16x32_bf16(
              af[mi], bfr[ni], acc[mi][ni], 0, 0, 0);
    } else {
      #pragma unroll
      for (int kf = 0; kf < 2; ++kf) {
        frag8 af[4], bfr[4];
        #pragma unroll
        for (int t = 0; t < 4; ++t) {
          const int ra = wm + t * 16 + l15;
          af[t] = *(const frag8*)((const char*)&sAm[cur][0] +
                    ra * 128 + ((kf * 64 + quad * 16) ^ ((ra & 7) << 4)));
          const int rb = wn + t * 16 + l15;
          bfr[t] = *(const frag8*)((const char*)&sBm[cur][0] +
                    rb * 128 + ((kf * 64 + quad * 16) ^ ((rb & 7) << 4)));
        }
        #pragma unroll
        for (int mi = 0; mi < 4; ++mi)
          #pragma unroll
          for (int ni = 0; ni < 4; ++ni)
            acc[mi][ni] = __builtin_amdgcn_mfma_f32_16x16x32_bf16(
                af[mi], bfr[ni], acc[mi][ni], 0, 0, 0);
      }
    }
    __syncthreads();   // drains vmcnt (next slice landed) + lgkm (reads done)
    cur ^= 1;
  }
  // all waves are past their LDS reads here: shared mem is reusable.

  if (mode == EP_KV && n0 >= 1024) {
    // ---- V half: LDS-transposed coalesced epilogue (BKT=32 only) ----
    short* smem = &sAm[0][0];   // 16384 shorts of scratch
    #pragma unroll
    for (int mi = 0; mi < 4; ++mi) {
      #pragma unroll
      for (int reg = 0; reg < 4; ++reg) {
        const int rowl = wm + mi * 16 + quad * 4 + reg;
        const int bbl  = rowl & 7;
        const int tl   = rowl >> 3;
        #pragma unroll
        for (int ni = 0; ni < 4; ++ni) {
          const int coll = wn + ni * 16 + l15;          // 0..127
          const int hn2  = coll >> 6;
          const int d    = coll & 63;
          const int rowid = (bbl * 2 + hn2) * 64 + d;
          smem[tl * 1024 + (rowid ^ (tl << 1))] =
              (short)bfbits(acc[mi][ni][reg]);
        }
      }
    }
    __syncthreads();
    // read phase: each thread emits 4 vT rows (16 t each) as 2x16B stores
    const int hnb = (n0 >> 6) - 16;        // head base for this block
    const int t0  = m0 >> 3;
    #pragma unroll
    for (int p = 0; p < 4; ++p) {
      const int r   = p * 256 + tid;       // rowid 0..1023
      const int bbl = r >> 7;
      const int hn2 = (r >> 6) & 1;
      const int d   = r & 63;
      unsigned short tmp[16];
      #pragma unroll
      for (int tl = 0; tl < 16; ++tl)
        tmp[tl] = (unsigned short)smem[tl * 1024 + (r ^ (tl << 1))];
      bf16* dst = vto + ((size_t)(bbl * 16 + hnb + hn2) * 64 + d) * 1024 + t0;
      *(frag8*)dst       = *(const frag8*)&tmp[0];
      *(frag8*)(dst + 8) = *(const frag8*)&tmp[8];
    }
    return;
  }

  #pragma unroll
  for (int mi = 0; mi < 4; ++mi) {
    #pragma unroll
    for (int reg = 0; reg < 4; ++reg) {
      const int rowl = wm + mi * 16 + quad * 4 + reg;
      const int row  = m0 + rowl;
      if (mode == EP_PLAIN) {
        bf16* orow = out + (size_t)row * N;
        const TRES* rrow = res ? res + (size_t)row * N : nullptr;
        #pragma unroll
        for (int ni = 0; ni < 4; ++ni) {
          const int col = n0 + wn + ni * 16 + l15;
          float v = acc[mi][ni][reg];
          if (bias) v += bias[col];
          if (relu) v = fmaxf(v, 0.f);
          if (rrow) v += tof(rrow[col]);
          orow[col] = f2bf(v);
        }
      } else if (mode == EP_PART) {
        // split-K partial: raw f32 accumulator to pout[s]
        float* prow = pout + (size_t)s * M * N + (size_t)row * N;
        #pragma unroll
        for (int ni = 0; ni < 4; ++ni) {
          const int col = n0 + wn + ni * 16 + l15;
          prow[col] = acc[mi][ni][reg];
        }
      } else if (mode == EP_KV) {
        // K half (n0 < 1024): direct stores, 32B/quad chunks
        const int t = row >> 3, bb = row & 7;
        #pragma unroll
        for (int ni = 0; ni < 4; ++ni) {
          const int col = n0 + wn + ni * 16 + l15;
          const int hn = col >> 6, d = col & 63;
          kbo[((size_t)(bb * 16 + hn) * 1024 + t) * 64 + d] =
              f2bf(acc[mi][ni][reg]);
        }
      } else if (mode == EP_Q) {
        // rows are cat rows 4096.. -> t = 512 + row>>3, tq = row>>3
        const int tq = row >> 3, bb = row & 7;
        #pragma unroll
        for (int ni = 0; ni < 4; ++ni) {
          const int col = n0 + wn + ni * 16 + l15;  // 0..1023
          const int hn = col >> 6, d = col & 63;
          const float v = acc[mi][ni][reg];
          const size_t idx = ((size_t)(bb * 16 + hn) * 512 + tq) * 64 + d;
          qwb[idx] = f2bf(v + rwbias[col]);
          qrb[idx] = f2bf(v + rrbias[col]);
        }
      } else { // EP_RK
        #pragma unroll
        for (int ni = 0; ni < 4; ++ni) {
          const int col = n0 + wn + ni * 16 + l15;
          const int hn = col >> 6, d = col & 63;
          qwb[((size_t)hn * 1024 + row) * 64 + d] = f2bf(acc[mi][ni][reg]);
        }
      }
    }
  }
}

// Fused MFMA attention v10: DS-pipe diet, allocation-clean (R10: 97 -> <94us;
// DS ops/wave-tile ~98 -> ~54 via dedup'd shuffles + DPP reduces).
__global__ __launch_bounds__(256, 4)
void fattn(const bf16* __restrict__ qw, const bf16* __restrict__ qr,
           const bf16* __restrict__ kb, const bf16* __restrict__ vT,
           const bf16* __restrict__ rk, bf16* __restrict__ avec)
{
  __shared__ __align__(16) short sK[4096];   // 64 j x 64 d bf16, swizzled (8 KB)
  __shared__ __align__(16) short sV[4096];   // 64 d x 64 j bf16, swizzled (8 KB)
  __shared__ __align__(16) unsigned short p_lds[4][16][64]; // 8 KB, XOR layout
  const int tid  = threadIdx.x;
  const int wave = tid >> 6, lane = tid & 63;
  const int quad = lane >> 4, l15 = lane & 15;
  // XCD-locality decode: bid = r + 8*(phi + 16*it), pair = r + 8*phi
  const int bid = blockIdx.x;
  const int r_  = bid & 7;
  const int s_  = bid >> 3;
  const int phi = s_ & 15;
  const int it  = s_ >> 4;            // i-tile 0..7
  const int pr  = r_ + 8 * phi;       // (h,b) pair 0..127
  const int h   = pr & 15;
  const int b   = pr >> 4;
  const int i0  = it * 64;
  const int iw  = i0 + wave * 16;
  const size_t bh = (size_t)b * 16 + h;
  const bf16* kp = kb + bh * 1024 * 64;
  const bf16* vp = vT + bh * 64 * 1024;
  const bf16* rp = rk + (size_t)h * 1024 * 64;

  frag8 aqw[2], aqr[2];
  {
    const bf16* r0 = qw + (bh * 512 + iw + l15) * 64 + quad * 8;
    aqw[0] = *(const frag8*)r0;
    aqw[1] = *(const frag8*)(r0 + 32);
    const bf16* r1 = qr + (bh * 512 + iw + l15) * 64 + quad * 8;
    aqr[0] = *(const frag8*)r1;
    aqr[1] = *(const frag8*)(r1 + 32);
  }

  f32x4 accO[4] = {};
  float m_run[4], l_run[4];
  #pragma unroll
  for (int rg = 0; rg < 4; ++rg) { m_run[rg] = -INFINITY; l_run[rg] = 0.f; }

  // block-uniform step count (i_last = i0+63); low waves' extra tiles are
  // fully masked (s=-inf -> pv=0 -> no contribution)
  const int nsteps = ((i0 + 63 + 512) >> 6) + 1;
  const int offb   = 15 + l15 - quad * 4;

  // stage j-tile [j0s, j0s+64) of K and V into sK/sV (8 KB each).
  // Linear LDS write (gload_lds, 2 chunks of 4 KB), inverse-swizzled source:
  //   content(byte Lb) = src[Lb ^ ((row&7)<<4)], row = Lb>>7 (128 B rows)
  auto stage = [&](int j0s) {
    #pragma unroll
    for (int c = 0; c < 2; ++c) {
      const int Lb = c * 4096 + tid * 16;
      const int r  = Lb >> 7;            // j-row (K) / d-row (V), 0..63
      const int xb = (Lb & 127) ^ ((r & 7) << 4);
      short* dK = (short*)((char*)sK + (c * 4096 + wave * 1024));
      short* dV = (short*)((char*)sV + (c * 4096 + wave * 1024));
      gload_lds16((const bf16*)((const char*)kp + ((size_t)j0s + r) * 128 + xb), dK);
      gload_lds16((const bf16*)((const char*)vp + (size_t)r * 2048 + (size_t)j0s * 2 + xb), dV);
    }
  };
  stage(0);

  for (int jt = 0; jt < nsteps; ++jt) {
    const int j0 = jt << 6;
    // ---- BD first: global rk loads (L2-resident) overlap K/V staging ----
    const int pbase = 496 + j0 - iw;
    f32x4 bsub[5];
    #pragma unroll
    for (int ns = 0; ns < 5; ++ns) {
      const int prow = min(pbase + ns * 16 + l15, 1023);
      const bf16* rrow = rp + (size_t)prow * 64 + quad * 8;
      frag8 br0 = *(const frag8*)rrow;
      frag8 br1 = *(const frag8*)(rrow + 32);
      f32x4 z = {};
      z = __builtin_amdgcn_mfma_f32_16x16x32_bf16(aqr[0], br0, z, 0,0,0);
      bsub[ns] = __builtin_amdgcn_mfma_f32_16x16x32_bf16(aqr[1], br1, z, 0,0,0);
    }
    __syncthreads();   // sK/sV for this tile are resident
    // ---- AC scores from sK (swizzled ds_read_b128) ----
    f32x4 accS[4] = {};
    #pragma unroll
    for (int ns = 0; ns < 4; ++ns) {
      const int row = ns * 16 + l15;
      const int sw  = (row & 7) << 4;
      frag8 bk0 = *(const frag8*)((const char*)sK + ((row * 128 + quad * 16) ^ sw));
      frag8 bk1 = *(const frag8*)((const char*)sK + ((row * 128 + 64 + quad * 16) ^ sw));
      accS[ns] = __builtin_amdgcn_mfma_f32_16x16x32_bf16(aqw[0], bk0, accS[ns], 0,0,0);
      accS[ns] = __builtin_amdgcn_mfma_f32_16x16x32_bf16(aqw[1], bk1, accS[ns], 0,0,0);
    }
    // ---- shift (dedup'd bpermutes, NAMED scalars) + combine + mask + max ----
    float tmax[4];
    #pragma unroll
    for (int rg = 0; rg < 4; ++rg) {
      const int o    = offb - rg;                 // [0,30]
      const int srcl = (quad << 4) | (o & 15);
      const float s0 = __shfl(bsub[0][rg], srcl, 64);
      const float s1 = __shfl(bsub[1][rg], srcl, 64);
      const float s2 = __shfl(bsub[2][rg], srcl, 64);
      const float s3 = __shfl(bsub[3][rg], srcl, 64);
      const float s4 = __shfl(bsub[4][rg], srcl, 64);
      const bool hi  = (o & 16) != 0;
      const float bd0 = hi ? s1 : s0;
      const float bd1 = hi ? s2 : s1;
      const float bd2 = hi ? s3 : s2;
      const float bd3 = hi ? s4 : s3;
      const int jb   = j0 + l15;
      const int lim  = iw + quad * 4 + rg + 512;
      float v0 = (accS[0][rg] + bd0) * 0.125f;
      float v1 = (accS[1][rg] + bd1) * 0.125f;
      float v2 = (accS[2][rg] + bd2) * 0.125f;
      float v3 = (accS[3][rg] + bd3) * 0.125f;
      v0 = (jb      > lim) ? -INFINITY : v0;
      v1 = (jb + 16 > lim) ? -INFINITY : v1;
      v2 = (jb + 32 > lim) ? -INFINITY : v2;
      v3 = (jb + 48 > lim) ? -INFINITY : v3;
      accS[0][rg] = v0; accS[1][rg] = v1; accS[2][rg] = v2; accS[3][rg] = v3;
      tmax[rg] = rowmax16(fmaxf(fmaxf(v0, v1), fmaxf(v2, v3)));
    }
    // ---- online softmax update (tsum via DPP row-sum, no DS reduce) ----
    float alpha[4], tsum[4] = {0.f, 0.f, 0.f, 0.f};
    #pragma unroll
    for (int rg = 0; rg < 4; ++rg) {
      const float nm = fmaxf(m_run[rg], tmax[rg]);
      alpha[rg] = __expf(m_run[rg] - nm);
      m_run[rg] = nm;
    }
    #pragma unroll
    for (int ns = 0; ns < 4; ++ns)
      #pragma unroll
      for (int rg = 0; rg < 4; ++rg) {
        const int rl = quad * 4 + rg;
        const float pv = __expf(accS[ns][rg] - m_run[rg]);
        tsum[rg] += pv;
        // XOR-compacted p_lds write (16B-granular, matches frag8 read)
        *(unsigned short*)((char*)&p_lds[wave][rl][0] +
            (((ns * 16 + l15) * 2) ^ ((rl & 7) << 4))) = bfbits(pv);
      }
    #pragma unroll
    for (int rg = 0; rg < 4; ++rg) {
      l_run[rg] = l_run[rg] * alpha[rg] + rowsum16(tsum[rg]);
      #pragma unroll
      for (int nd = 0; nd < 4; ++nd)
        accO[nd][rg] *= alpha[rg];
    }
    __builtin_amdgcn_wave_barrier();
    // ---- PV from sV (swizzled ds_read_b128) ----
    #pragma unroll
    for (int ks = 0; ks < 2; ++ks) {
      frag8 ap = *(const frag8*)((const char*)&p_lds[wave][l15][0] +
                  ((ks * 64 + quad * 16) ^ ((l15 & 7) << 4)));
      #pragma unroll
      for (int nd = 0; nd < 4; ++nd) {
        const int d = nd * 16 + l15;
        frag8 bv = *(const frag8*)((const char*)sV +
                    ((d * 128 + ks * 64 + quad * 16) ^ ((d & 7) << 4)));
        accO[nd] = __builtin_amdgcn_mfma_f32_16x16x32_bf16(ap, bv, accO[nd], 0,0,0);
      }
    }
    __builtin_amdgcn_wave_barrier();
    __syncthreads();   // all waves done reading sK/sV
    if (jt + 1 < nsteps) stage((jt + 1) << 6);
  }

  #pragma unroll
  for (int rg = 0; rg < 4; ++rg) {
    const int i = iw + quad * 4 + rg;
    const float inv = 1.f / l_run[rg];
    #pragma unroll
    for (int nd = 0; nd < 4; ++nd) {
      const int d = nd * 16 + l15;
      avec[((size_t)i * 8 + b) * 1024 + h * 64 + d] = f2bf(accO[nd][rg] * inv);
    }
  }
}

// row LayerNorm over 1024 cols; one block per row.
template<typename TOUT>
__global__ __launch_bounds__(256)
void ln_kernel(const bf16* __restrict__ x, const float* __restrict__ g,
               const float* __restrict__ be, TOUT* __restrict__ out)
{
  __shared__ float red0[4];
  __shared__ float red1[4];
  const int row = blockIdx.x;
  const int tid = threadIdx.x;
  const bf16* xr = x + (size_t)row * 1024;
  ushort4 u = *(const ushort4*)(xr + (tid << 2));
  const float v0 = u16f(u.x), v1 = u16f(u.y), v2 = u16f(u.z), v3 = u16f(u.w);
  float sum = v0 + v1 + v2 + v3;
  #pragma unroll
  for (int off = 1; off < 64; off <<= 1) sum += __shfl_xor(sum, off, 64);
  if ((tid & 63) == 0) red0[tid >> 6] = sum;
  __syncthreads();
  const float mu = (red0[0] + red0[1] + red0[2] + red0[3]) * (1.f / 1024.f);
  const float d0 = v0 - mu, d1 = v1 - mu, d2 = v2 - mu, d3 = v3 - mu;
  float sq = d0*d0 + d1*d1 + d2*d2 + d3*d3;
  #pragma unroll
  for (int off = 1; off < 64; off <<= 1) sq += __shfl_xor(sq, off, 64);
  if ((tid & 63) == 0) red1[tid >> 6] = sq;
  __syncthreads();
  const float var = (red1[0] + red1[1] + red1[2] + red1[3]) * (1.f / 1024.f);
  const float inv = 1.f / sqrtf(var + 1e-5f);
  const int c = tid << 2;
  float4 ug = *(const float4*)(g + c);
  float4 ub = *(const float4*)(be + c);
  TOUT* orow = out + (size_t)row * 1024;
  orow[c+0] = (TOUT)(d0 * inv * ug.x + ub.x);
  orow[c+1] = (TOUT)(d1 * inv * ug.y + ub.y);
  orow[c+2] = (TOUT)(d2 * inv * ug.z + ub.z);
  orow[c+3] = (TOUT)(d3 * inv * ug.w + ub.w);
}

// fused split-K reduce + LayerNorm: x = res + p0 + p1 (+ bias), out = LN(x).
// TRES = float (w residual, LN1) or bf16 (o1 residual, LN2).
template<typename TOUT, typename TRES>
__global__ __launch_bounds__(256)
void ln_red(const float* __restrict__ p0, const float* __restrict__ p1,
            const TRES* __restrict__ res, const float* __restrict__ bias,
            const float* __restrict__ g, const float* __restrict__ be,
            TOUT* __restrict__ out)
{
  __shared__ float red0[4];
  __shared__ float red1[4];
  const int row = blockIdx.x;
  const int tid = threadIdx.x;
  const int c = tid << 2;
  const size_t base = (size_t)row * 1024 + c;
  float4 a0 = *(const float4*)(p0 + base);
  float4 a1 = *(const float4*)(p1 + base);
  float r0, r1, r2, r3;
  if constexpr (sizeof(TRES) == 4) {
    float4 rv = *(const float4*)((const float*)res + base);
    r0 = rv.x; r1 = rv.y; r2 = rv.z; r3 = rv.w;
  } else {
    ushort4 u = *(const ushort4*)((const bf16*)res + base);
    r0 = u16f(u.x); r1 = u16f(u.y); r2 = u16f(u.z); r3 = u16f(u.w);
  }
  float b0 = 0.f, b1 = 0.f, b2 = 0.f, b3 = 0.f;
  if (bias) {
    float4 bv = *(const float4*)(bias + c);
    b0 = bv.x; b1 = bv.y; b2 = bv.z; b3 = bv.w;
  }
  const float v0 = r0 + a0.x + a1.x + b0;
  const float v1 = r1 + a0.y + a1.y + b1;
  const float v2 = r2 + a0.z + a1.z + b2;
  const float v3 = r3 + a0.w + a1.w + b3;
  float sum = v0 + v1 + v2 + v3;
  #pragma unroll
  for (int off = 1; off < 64; off <<= 1) sum += __shfl_xor(sum, off, 64);
  if ((tid & 63) == 0) red0[tid >> 6] = sum;
  __syncthreads();
  const float mu = (red0[0] + red0[1] + red0[2] + red0[3]) * (1.f / 1024.f);
  const float d0 = v0 - mu, d1 = v1 - mu, d2 = v2 - mu, d3 = v3 - mu;
  float sq = d0*d0 + d1*d1 + d2*d2 + d3*d3;
  #pragma unroll
  for (int off = 1; off < 64; off <<= 1) sq += __shfl_xor(sq, off, 64);
  if ((tid & 63) == 0) red1[tid >> 6] = sq;
  __syncthreads();
  const float var = (red1[0] + red1[1] + red1[2] + red1[3]) * (1.f / 1024.f);
  const float inv = 1.f / sqrtf(var + 1e-5f);
  float4 ug = *(const float4*)(g + c);
  float4 ub = *(const float4*)(be + c);
  TOUT* orow = out + (size_t)row * 1024;
  orow[c+0] = (TOUT)(d0 * inv * ug.x + ub.x);
  orow[c+1] = (TOUT)(d1 * inv * ug.y + ub.y);
  orow[c+2] = (TOUT)(d2 * inv * ug.z + ub.z);
  orow[c+3] = (TOUT)(d3 * inv * ug.w + ub.w);
}

extern "C" void kernel_launch(void* const* d_in, const int* in_sizes, int n_in,
                              void* d_out, int out_size, void* d_ws, size_t ws_size,
                              hipStream_t stream)
{
  const float* w    = (const float*)d_in[0];
  const float* r    = (const float*)d_in[1];
  const float* rwb  = (const float*)d_in[2];
  const float* rrb  = (const float*)d_in[3];
  const float* mems = (const float*)d_in[4];
  // d_in[5] = attn_mask: deterministic (j > i + 512), computed in-kernel
  const float* Wqkv = (const float*)d_in[6];
  const float* Wr   = (const float*)d_in[7];
  const float* Wo   = (const float*)d_in[8];
  const float* ln1g = (const float*)d_in[9];
  const float* ln1b = (const float*)d_in[10];
  const float* W1   = (const float*)d_in[11];
  const float* b1   = (const float*)d_in[12];
  const float* W2   = (const float*)d_in[13];
  const float* b2   = (const float*)d_in[14];
  const float* ln2g = (const float*)d_in[15];
  const float* ln2b = (const float*)d_in[16];

  // Workspace (bf16), liveness-aliased, peak 94 MiB.
  // R13: Wo partials (2x16MB f32) at 58-90 (dead K/V region, consumed by
  // ln_red before FF1 overwrites with h); FF2 partials at 0-32 (dead
  // avec/x1/catb region).
  const size_t MB = 1u << 20;
  char* p = (char*)d_ws;
  bf16* catb  = (bf16*)(p +  0 * MB);
  bf16* wqkvb = (bf16*)(p + 16 * MB);
  bf16* wrb   = (bf16*)(p + 22 * MB);
  bf16* wob   = (bf16*)(p + 24 * MB);
  bf16* w1b   = (bf16*)(p + 26 * MB);
  bf16* w2b   = (bf16*)(p + 34 * MB);
  bf16* qwbuf = (bf16*)(p + 42 * MB);
  bf16* qrbuf = (bf16*)(p + 50 * MB);
  bf16* kbuf  = (bf16*)(p + 58 * MB);
  bf16* vTbuf = (bf16*)(p + 74 * MB);
  bf16* rkbuf = (bf16*)(p + 90 * MB);
  bf16* rb    = (bf16*)(p + 92 * MB);
  bf16* avec  = (bf16*)(p +  0 * MB);
  bf16* o1    = (bf16*)(p + 42 * MB);
  bf16* h     = (bf16*)(p + 58 * MB);
  float* woP  = (float*)(p + 58 * MB);   // Wo partials: 2 x 16 MB
  float* ffP  = (float*)(p +  0 * MB);   // FF2 partials: 2 x 16 MB

  dim3 blk(256);
  // 0. fp32 -> bf16 converts (one batched launch)
  {
    CvtArgs a;
    const int n4w = (4096 * 1024) / 4, n4r = (1024 * 1024) / 4,
              n4qkv = (3072 * 1024) / 4;
    a.src[0] = mems; a.dst[0] = catb;                        int n0_ = n4w;
    a.src[1] = w;    a.dst[1] = catb + (size_t)4096 * 1024;  int n1_ = n4w;
    a.src[2] = r;    a.dst[2] = rb;                          int n2_ = n4r;
    a.src[3] = Wqkv; a.dst[3] = wqkvb;                       int n3_ = n4qkv;
    a.src[4] = Wr;   a.dst[4] = wrb;                         int n4_ = n4r;
    a.src[5] = Wo;   a.dst[5] = wob;                         int n5_ = n4r;
    a.src[6] = W1;   a.dst[6] = w1b;                         int n6_ = n4w;
    a.src[7] = W2;   a.dst[7] = w2b;                         int n7_ = n4w;
    const int ns_[8] = {n0_, n1_, n2_, n3_, n4_, n5_, n6_, n7_};
    a.cum[0] = 0;
    for (int s2 = 0; s2 < 8; ++s2) a.cum[s2 + 1] = a.cum[s2] + ns_[s2];
    cvt8<<<dim3((a.cum[8] + 255) / 256), blk, 0, stream>>>(a);
  }

  // 1a. K/V projection: cat @ Wqkv[1024:3072]^T -> kb + vT (LDS-coalesced)
  mgemm<float, 32><<<dim3(1024), blk, 0, stream>>>(catb, wqkvb + (size_t)1024 * 1024,
        nullptr, (const float*)nullptr, nullptr, nullptr, nullptr, nullptr, kbuf, vTbuf,
        nullptr, nullptr, 8192, 2048, 1024, 1024, EP_KV, 0, 16, 16, 8, 1024);
  // 1b. Q projection: rows t>=512 only
  mgemm<float, 64><<<dim3(256), blk, 0, stream>>>(catb + (size_t)4096 * 1024, wqkvb,
        nullptr, (const float*)nullptr, nullptr, nullptr, qwbuf, qrbuf, nullptr, nullptr,
        rwb, rrb, 4096, 1024, 1024, 1024, EP_Q, 0, 8, 4, 8, 256);
  // 2. rk = r @ Wr^T
  mgemm<float, 64><<<dim3(64), blk, 0, stream>>>(rb, wrb, nullptr, (const float*)nullptr,
        nullptr, nullptr, rkbuf, nullptr, nullptr, nullptr, nullptr, nullptr,
        1024, 1024, 1024, 1024, EP_RK, 0, 8, 2, 4, 64);
  // 3. fused MFMA attention -> avec
  fattn<<<dim3(1024), blk, 0, stream>>>(qwbuf, qrbuf, kbuf, vTbuf, rkbuf, avec);
  // 4. avec @ Wo^T split-K=2 -> woP[0], woP[1] (f32 partials)
  mgemm<float, 64><<<dim3(512), blk, 0, stream>>>(avec, wob, nullptr, (const float*)nullptr,
        nullptr, woP, nullptr, nullptr, nullptr, nullptr, nullptr, nullptr,
        4096, 1024, 512, 1024, EP_PART, 0, 8, 4, 8, 256);
  // 5. out1 = LN(w + p0 + p1)
  ln_red<bf16, float><<<dim3(4096), blk, 0, stream>>>(
        woP, woP + (size_t)4096 * 1024, w, nullptr, ln1g, ln1b, o1);
  // 6. h = relu(out1 @ W1^T + b1)
  mgemm<float, 32><<<dim3(1024), blk, 0, stream>>>(o1, w1b, b1, (const float*)nullptr,
        h, nullptr, nullptr, nullptr, nullptr, nullptr, nullptr, nullptr,
        4096, 4096, 1024, 1024, EP_PLAIN, 1, 32, 8, 16, 1024);
  // 7. h @ W2^T split-K=2 -> ffP[0], ffP[1]
  mgemm<bf16, 64><<<dim3(512), blk, 0, stream>>>(h, w2b, nullptr, (const bf16*)nullptr,
        nullptr, ffP, nullptr, nullptr, nullptr, nullptr, nullptr, nullptr,
        4096, 1024, 2048, 4096, EP_PART, 0, 8, 4, 8, 256);
  // 8. out = LN(o1 + p0 + p1 + b2) -> fp32
  ln_red<float, bf16><<<dim3(4096), blk, 0, stream>>>(
        ffP, ffP + (size_t)4096 * 1024, o1, b2, ln2g, ln2b, (float*)d_out);
}